// Round 8
// baseline (577.162 us; speedup 1.0000x reference)
//
#include <hip/hip_runtime.h>
#include <hip/hip_bf16.h>

typedef __attribute__((ext_vector_type(8))) short bf16x8;
typedef __attribute__((ext_vector_type(4))) float f32x4;
typedef __attribute__((ext_vector_type(4))) unsigned int u32x4;

#define B_N   4
#define C_IN  32
#define C_OUT 64
#define S_H   32
#define S_W   64
#define S_D   64
#define HWD   (S_H * S_W * S_D)   /* 131072 */

// ws layout: [Wpk 4*28*64*8 ushorts][Zpf 16 floats]
#define WPK_USHORTS     (4 * 28 * 64 * 8)              /* 57344 */
#define WS_NEEDED       ((size_t)WPK_USHORTS * 2 + 64)

__device__ __forceinline__ ushort f2bf(float f) {
    unsigned u = __builtin_bit_cast(unsigned, f);
    unsigned r = (u + 0x7FFFu + ((u >> 16) & 1u)) >> 16;  // RNE
    return (ushort)r;
}

// packed f32x2 -> bf16x2 (RNE), single VALU op
__device__ __forceinline__ unsigned cvt_pk(float lo, float hi) {
    unsigned r;
    asm("v_cvt_pk_bf16_f32 %0, %1, %2" : "=v"(r) : "v"(lo), "v"(hi));
    return r;
}

typedef const __attribute__((address_space(1))) unsigned int* dma_gptr;
typedef __attribute__((address_space(3))) unsigned int* dma_lptr;

__device__ __forceinline__ void dma16(const void* g, void* l) {
    __builtin_amdgcn_global_load_lds((dma_gptr)g, (dma_lptr)l, 16, 0, 0);
}

// pinned async global load: issued exactly here, untracked by the legalizer;
// consumer MUST execute an explicit s_waitcnt vmcnt before reading dst.
__device__ __forceinline__ void pin_load(float& dst, const float* p) {
    asm volatile("global_load_dword %0, %1, off" : "=v"(dst) : "v"(p));
}

// keep a 128-bit value (4 VGPRs) live without cost (rule #17 anti-DCE)
__device__ __forceinline__ void keep(const bf16x8& v) {
    u32x4 u = __builtin_bit_cast(u32x4, v);
    asm volatile("" :: "v"(u[0]), "v"(u[1]), "v"(u[2]), "v"(u[3]));
}

// ---- prep: pack weights [cic][tap28][co64][ci8] bf16; also zero-page -----
__global__ __launch_bounds__(256) void pack_w_kernel(
    const float* __restrict__ Wt, ushort* __restrict__ Wpk, float* __restrict__ Zpf)
{
    int idx = blockIdx.x * 256 + threadIdx.x;       // 4*28*64 = 7168
    int cic = idx / 1792;
    int r   = idx - cic * 1792;
    int tap = r >> 6;
    int co  = r & 63;
    bf16x8 pk;
    #pragma unroll
    for (int j = 0; j < 8; ++j)
        pk[j] = (tap < 27) ? (short)f2bf(Wt[((long)co * C_IN + cic * 8 + j) * 27 + tap])
                           : (short)0;
    *((bf16x8*)Wpk + idx) = pk;
    if (blockIdx.x == 0 && threadIdx.x < 16) Zpf[threadIdx.x] = 0.f;
}

// ---- main + ablations ------------------------------------------------------
// V=0 FULL (R5 base + cvt_pk; writes out)     V=1 NO_MFMA (reads kept alive)
// V=2 NO_DSREAD (MFMA on persistent regs)     V=3 NO_STAGE (no X/W/cvt/write)
// V=4 NO_XGLOBAL (staging kept, X loads cut)
// REP repeats the cic loop (REP=2 doubles loop time so ablation dispatches
// rank above V0/fills in the top-5 table). Epilogue runs once in all.
template<int V, int REP>
__global__ __launch_bounds__(256, 2) void conv_abl(
    const float* __restrict__ X, const ushort* __restrict__ Wpk,
    const float* __restrict__ Zpf,
    const float* __restrict__ bias, float* __restrict__ out)
{
    __shared__ ushort Xs[1188 * 8];      // [hh3][ww6][dpos66][ci8]  19008 B
    __shared__ ushort Ws[1792 * 8];      // [tap28][co64][ci8]       28672 B

    const int tid  = threadIdx.x;
    const int lane = tid & 63;
    const int wave = tid >> 6;
    const int nl   = lane & 15;
    const int quad = lane >> 4;

    const int blk = blockIdx.x;       // 2048 blocks = (b4, h32, wt16)
    const int wt  = blk & 15;
    const int h   = (blk >> 4) & 31;
    const int b   = blk >> 9;
    const int w0  = wt * 4;

    // ---- per-site X pointers; pad sites -> zero page with stride 0 --------
    const float* xb[5];
    int adv[5];
    #pragma unroll
    for (int k = 0; k < 5; ++k) {
        int s = tid + k * 256;
        xb[k] = Zpf; adv[k] = 0;
        if (s < 1188) {
            int hh   = s / 396;           // 6*66
            int r0   = s - hh * 396;
            int ww   = r0 / 66;
            int dpos = r0 - ww * 66;
            int hp  = h - 1 + hh;
            int wp2 = w0 - 1 + ww;
            int dp  = dpos - 1;
            bool ok = (unsigned)hp < S_H && (unsigned)wp2 < S_W && (unsigned)dp < S_D;
            if (ok) {
                xb[k]  = X + ((((long)b * C_IN) * S_H + hp) * S_W + wp2) * S_D + dp;
                adv[k] = HWD;
            }
        }
    }

    // ---- per-tg LDS offsets (ushort units) --------------------------------
    int a_off[7], b_off[7];
    #pragma unroll
    for (int tg = 0; tg < 7; ++tg) {
        int tap = tg * 4 + quad;
        int tb  = tap < 27 ? tap : 0;      // pad tap: A rows are zero anyway
        int kh = tb / 9;
        int r9 = tb - kh * 9;
        int kw = r9 / 3;
        int kd = r9 - kw * 3;
        a_off[tg] = (tap * 64 + nl) * 8;
        b_off[tg] = (((kh * 6 + kw + wave) * 66) + kd + nl) * 8;  // ww = wave+kw
    }

    float bs[16];
    #pragma unroll
    for (int mi = 0; mi < 4; ++mi)
        #pragma unroll
        for (int r = 0; r < 4; ++r)
            bs[mi * 4 + r] = bias[mi * 16 + quad * 4 + r];

    f32x4 acc[16];
    #pragma unroll
    for (int i = 0; i < 16; ++i) acc[i] = (f32x4){0.f, 0.f, 0.f, 0.f};

    float xv[5][8];
    if constexpr (V == 3 || V == 4) {
        #pragma unroll
        for (int k = 0; k < 5; ++k)
            #pragma unroll
            for (int j = 0; j < 8; ++j) xv[k][j] = (float)(tid + k * 8 + j);
    }

    // persistent MFMA operands for the NO_DSREAD variant
    bf16x8 af_p[4], bf_p[4];
    if constexpr (V == 2) {
        #pragma unroll
        for (int mi = 0; mi < 4; ++mi)
            #pragma unroll
            for (int j = 0; j < 8; ++j) {
                af_p[mi][j] = (short)(tid * 7 + mi * 8 + j);
                bf_p[mi][j] = (short)(tid * 5 + mi * 8 + j + 1);
            }
    }

    // ---- prologue: pinned X loads chunk 0 + W chunk 0 DMA + stage ---------
    if constexpr (V == 0 || V == 1 || V == 2) {
        #pragma unroll
        for (int k = 0; k < 5; ++k) {
            int s = tid + k * 256;
            if (s < 1188) {
                #pragma unroll
                for (int j = 0; j < 8; ++j)
                    pin_load(xv[k][j], xb[k] + (long)j * adv[k]);
            }
        }
        __builtin_amdgcn_sched_barrier(0);
    }
    if constexpr (V != 3) {
        #pragma unroll
        for (int k = 0; k < 7; ++k) {
            int s = tid + k * 256;
            dma16(Wpk + s * 8, &Ws[s * 8]);
        }
        __builtin_amdgcn_sched_barrier(0);
    }
    if constexpr (V == 0 || V == 1 || V == 2) {
        asm volatile("s_waitcnt vmcnt(7)" ::: "memory");  // X drained, W in flight
        __builtin_amdgcn_sched_barrier(0);
    }
    if constexpr (V != 3) {
        #pragma unroll
        for (int k = 0; k < 5; ++k) {
            int s = tid + k * 256;
            if (s < 1188) {
                u32x4 pk;
                #pragma unroll
                for (int j = 0; j < 4; ++j)
                    pk[j] = cvt_pk(xv[k][2 * j], xv[k][2 * j + 1]);
                *(u32x4*)&Xs[s * 8] = pk;
            }
        }
    }

    #pragma unroll 1
    for (int it = 0; it < 4 * REP; ++it) {
        const bool more = (it < 4 * REP - 1);
        const int  cn   = (it + 1) & 3;

        __syncthreads();                 // drains W DMA; Xs chunk visible

        if constexpr (V == 0 || V == 1 || V == 2) {
            if (more) {
                #pragma unroll
                for (int k = 0; k < 5; ++k) {
                    int s = tid + k * 256;
                    if (s < 1188) {
                        #pragma unroll
                        for (int j = 0; j < 8; ++j)
                            pin_load(xv[k][j], xb[k] + (long)(cn * 8 + j) * adv[k]);
                    }
                }
            }
            __builtin_amdgcn_sched_barrier(0);   // loads stay above compute
        }

        #pragma unroll
        for (int tg = 0; tg < 7; ++tg) {
            bf16x8 af[4], bf[4];
            if constexpr (V != 2) {
                #pragma unroll
                for (int mi = 0; mi < 4; ++mi)
                    af[mi] = *(const bf16x8*)&Ws[a_off[tg] + mi * 128];
                #pragma unroll
                for (int dt = 0; dt < 4; ++dt)
                    bf[dt] = *(const bf16x8*)&Xs[b_off[tg] + dt * 128];
            } else {
                #pragma unroll
                for (int mi = 0; mi < 4; ++mi) { af[mi] = af_p[mi]; bf[mi] = bf_p[mi]; }
            }
            if constexpr (V == 1) {
                #pragma unroll
                for (int mi = 0; mi < 4; ++mi) keep(af[mi]);
                #pragma unroll
                for (int dt = 0; dt < 4; ++dt) keep(bf[dt]);
            } else {
                #pragma unroll
                for (int mi = 0; mi < 4; ++mi)
                    #pragma unroll
                    for (int dt = 0; dt < 4; ++dt)
                        acc[mi * 4 + dt] = __builtin_amdgcn_mfma_f32_16x16x32_bf16(
                            af[mi], bf[dt], acc[mi * 4 + dt], 0, 0, 0);
            }
        }

        if (more) {
            __syncthreads();             // compute done; safe to overwrite LDS
            if constexpr (V == 0 || V == 1 || V == 2) {
                asm volatile("s_waitcnt vmcnt(0)" ::: "memory");  // X loads done
                __builtin_amdgcn_sched_barrier(0);
            }
            if constexpr (V != 3) {
                const ushort* src = Wpk + (long)cn * 1792 * 8;
                #pragma unroll
                for (int k = 0; k < 7; ++k) {
                    int s = tid + k * 256;
                    dma16(src + s * 8, &Ws[s * 8]);
                }
                #pragma unroll
                for (int k = 0; k < 5; ++k) {
                    int s = tid + k * 256;
                    if (s < 1188) {
                        u32x4 pk;
                        #pragma unroll
                        for (int j = 0; j < 4; ++j)
                            pk[j] = cvt_pk(xv[k][2 * j], xv[k][2 * j + 1]);
                        *(u32x4*)&Xs[s * 8] = pk;
                    }
                }
            }
        }
    }

    // ---- epilogue: co = mi*16 + quad*4 + r, n = (w0+wave, dt*16+nl) -------
    const int w = w0 + wave;
    #pragma unroll
    for (int mi = 0; mi < 4; ++mi) {
        #pragma unroll
        for (int dt = 0; dt < 4; ++dt) {
            f32x4 a = acc[mi * 4 + dt];
            int d0 = dt * 16 + nl;
            #pragma unroll
            for (int r = 0; r < 4; ++r) {
                int co = mi * 16 + quad * 4 + r;
                out[(((long)(b * C_OUT + co) * S_H + h) * S_W + w) * S_D + d0]
                    = a[r] + bs[mi * 4 + r];
            }
        }
    }
}

// ---- fallback (no workspace needed) ---------------------------------------
__global__ __launch_bounds__(256) void conv3d_mfma_fallback(
    const float* __restrict__ X, const float* __restrict__ Wt,
    const float* __restrict__ bias, float* __restrict__ out)
{
    __shared__ ushort Xs[3 * 6 * 66 * 8];
    __shared__ ushort Ws[28 * 64 * 8];

    const int tid  = threadIdx.x;
    const int lane = tid & 63;
    const int wave = tid >> 6;
    const int nl   = lane & 15;
    const int quad = lane >> 4;
    const int co_base = wave * 16;

    const int blk = blockIdx.x;
    const int wt  = blk & 15;
    const int h   = (blk >> 4) & 31;
    const int b   = blk >> 9;
    const int w0  = wt * 4;

    float bs[4];
    #pragma unroll
    for (int r = 0; r < 4; ++r) bs[r] = bias[co_base + quad * 4 + r];

    f32x4 acc[16];
    #pragma unroll
    for (int i = 0; i < 16; ++i) acc[i] = (f32x4){0.f, 0.f, 0.f, 0.f};

    for (int cic = 0; cic < 4; ++cic) {
        __syncthreads();
        for (int s = tid; s < 64 * 27; s += 256) {
            int co = s / 27;
            int t  = s - co * 27;
            const float* wp = Wt + ((long)co * C_IN + cic * 8) * 27 + t;
            bf16x8 pk;
            #pragma unroll
            for (int j = 0; j < 8; ++j) pk[j] = (short)f2bf(wp[j * 27]);
            *(bf16x8*)&Ws[(t * 64 + co) * 8] = pk;
        }
        for (int s = tid; s < 64; s += 256) {
            bf16x8 z;
            #pragma unroll
            for (int j = 0; j < 8; ++j) z[j] = 0;
            *(bf16x8*)&Ws[(27 * 64 + s) * 8] = z;
        }
        for (int s = tid; s < 1188; s += 256) {
            int hh   = s / 396;
            int r0   = s - hh * 396;
            int ww   = r0 / 66;
            int dpos = r0 - ww * 66;
            int hp = h - 1 + hh;
            int wp2 = w0 - 1 + ww;
            int dp = dpos - 1;
            bool ok = (unsigned)hp < S_H && (unsigned)wp2 < S_W && (unsigned)dp < S_D;
            int hc = min(max(hp, 0), S_H - 1);
            int wc = min(max(wp2, 0), S_W - 1);
            int dc = min(max(dp, 0), S_D - 1);
            const float* xp = X + (((long)(b * C_IN + cic * 8) * S_H + hc) * S_W + wc) * S_D + dc;
            bf16x8 pk;
            #pragma unroll
            for (int j = 0; j < 8; ++j) {
                float v = xp[(long)j * HWD];
                pk[j] = ok ? (short)f2bf(v) : (short)0;
            }
            *(bf16x8*)&Xs[s * 8] = pk;
        }
        __syncthreads();

        #pragma unroll
        for (int tg = 0; tg < 7; ++tg) {
            int tap = tg * 4 + quad;
            bf16x8 afrag = *(const bf16x8*)&Ws[(tap * 64 + co_base + nl) * 8];
            int tb = tap < 27 ? tap : 0;
            int kh = tb / 9;
            int r9 = tb - kh * 9;
            int kw = r9 / 3;
            int kd = r9 - kw * 3;
            int bbase = ((kh * 6 + kw) * 66 + kd + nl) * 8;
            #pragma unroll
            for (int wi = 0; wi < 4; ++wi) {
                #pragma unroll
                for (int dt = 0; dt < 4; ++dt) {
                    bf16x8 bfrag = *(const bf16x8*)&Xs[bbase + wi * (66 * 8) + dt * (16 * 8)];
                    acc[wi * 4 + dt] = __builtin_amdgcn_mfma_f32_16x16x32_bf16(
                        afrag, bfrag, acc[wi * 4 + dt], 0, 0, 0);
                }
            }
        }
    }

    #pragma unroll
    for (int wi = 0; wi < 4; ++wi) {
        int w = w0 + wi;
        #pragma unroll
        for (int dt = 0; dt < 4; ++dt) {
            int d0 = dt * 16 + nl;
            f32x4 a = acc[wi * 4 + dt];
            #pragma unroll
            for (int r = 0; r < 4; ++r) {
                int co = co_base + quad * 4 + r;
                out[(((long)(b * C_OUT + co) * S_H + h) * S_W + w) * S_D + d0] = a[r] + bs[r];
            }
        }
    }
}

extern "C" void kernel_launch(void* const* d_in, const int* in_sizes, int n_in,
                              void* d_out, int out_size, void* d_ws, size_t ws_size,
                              hipStream_t stream) {
    const float* X    = (const float*)d_in[0];
    const float* Wt   = (const float*)d_in[1];
    const float* bias = (const float*)d_in[2];
    float* out = (float*)d_out;

    if (ws_size >= WS_NEEDED) {
        ushort* Wpk = (ushort*)d_ws;
        float*  Zpf = (float*)((char*)d_ws + (size_t)WPK_USHORTS * 2);
        pack_w_kernel<<<dim3(28), dim3(256), 0, stream>>>(Wt, Wpk, Zpf);
        // ---- ablation dispatches (REP=2; garbage out, overwritten by V0) --
        conv_abl<1, 2><<<dim3(2048), dim3(256), 0, stream>>>(X, Wpk, Zpf, bias, out);
        conv_abl<2, 2><<<dim3(2048), dim3(256), 0, stream>>>(X, Wpk, Zpf, bias, out);
        conv_abl<3, 2><<<dim3(2048), dim3(256), 0, stream>>>(X, Wpk, Zpf, bias, out);
        conv_abl<4, 2><<<dim3(2048), dim3(256), 0, stream>>>(X, Wpk, Zpf, bias, out);
        // ---- the real kernel, LAST (writes correct out) -------------------
        conv_abl<0, 1><<<dim3(2048), dim3(256), 0, stream>>>(X, Wpk, Zpf, bias, out);
    } else {
        conv3d_mfma_fallback<<<dim3(2048), dim3(256), 0, stream>>>(X, Wt, bias, out);
    }
}

// Round 9
// 272.813 us; speedup vs baseline: 2.1156x; 2.1156x over previous
//
#include <hip/hip_runtime.h>
#include <hip/hip_bf16.h>

typedef __attribute__((ext_vector_type(8))) short bf16x8;
typedef __attribute__((ext_vector_type(4))) float f32x4;
typedef __attribute__((ext_vector_type(4))) unsigned int u32x4;

#define C_IN  32
#define C_OUT 64
#define S_H   32
#define S_W   64
#define S_D   64
#define HWD   (S_H * S_W * S_D)   /* 131072 */

// ws layout: [Wpk 114688 B][Zpf 64 B][Xpk 34.6 MB]
// Wpk: [cic4][tap28][co64][ci8] bf16 (tap27 row = zeros, doubles as OOB target)
// Xpk: [cic4][b4][h32][w64][dd66][ci8] bf16, dd = d+1 (d-halo baked in)
#define WPK_BYTES   (4 * 28 * 64 * 8 * 2)        /* 114688 */
#define ZPF_OFF     WPK_BYTES
#define XPK_OFF     (WPK_BYTES + 64)             /* 114752, 16B aligned */
#define XPK_SITES   (4 * 4 * 32 * 64 * 66)       /* 2,162,688 */
#define XPK_BYTES   ((size_t)XPK_SITES * 16)     /* 34,603,008 */
#define XPK_CIC_STR (4 * 32 * 64 * 66 * 16)      /* 8,650,752 B */
#define WS_FLAT     ((size_t)XPK_OFF + XPK_BYTES)
#define WS_FUSED    ((size_t)WPK_BYTES + 64)
#define WZERO_OFF   (27 * 1024)                  /* cic0 tap27 zero row (1 KB) */

__device__ __forceinline__ ushort f2bf(float f) {
    unsigned u = __builtin_bit_cast(unsigned, f);
    unsigned r = (u + 0x7FFFu + ((u >> 16) & 1u)) >> 16;  // RNE
    return (ushort)r;
}

// packed f32x2 -> bf16x2 (RNE), single VALU op
__device__ __forceinline__ unsigned cvt_pk(float lo, float hi) {
    unsigned r;
    asm("v_cvt_pk_bf16_f32 %0, %1, %2" : "=v"(r) : "v"(lo), "v"(hi));
    return r;
}

typedef const __attribute__((address_space(1))) unsigned int* dma_gptr;
typedef __attribute__((address_space(3))) unsigned int* dma_lptr;

__device__ __forceinline__ void dma16(const void* g, void* l) {
    __builtin_amdgcn_global_load_lds((dma_gptr)g, (dma_lptr)l, 16, 0, 0);
}

__device__ __forceinline__ void pin_load(float& dst, const float* p) {
    asm volatile("global_load_dword %0, %1, off" : "=v"(dst) : "v"(p));
}

// ---- prep: pack weights [cic][tap28][co64][ci8] bf16; zero-page ----------
__global__ __launch_bounds__(256) void pack_w_kernel(
    const float* __restrict__ Wt, ushort* __restrict__ Wpk, float* __restrict__ Zpf)
{
    int idx = blockIdx.x * 256 + threadIdx.x;       // 4*28*64 = 7168
    int cic = idx / 1792;
    int r   = idx - cic * 1792;
    int tap = r >> 6;
    int co  = r & 63;
    bf16x8 pk;
    #pragma unroll
    for (int j = 0; j < 8; ++j)
        pk[j] = (tap < 27) ? (short)f2bf(Wt[((long)co * C_IN + cic * 8 + j) * 27 + tap])
                           : (short)0;
    *((bf16x8*)Wpk + idx) = pk;
    if (blockIdx.x == 0 && threadIdx.x < 16) Zpf[threadIdx.x] = 0.f;
}

// ---- prep: pack X -> [cic][b][h][w][dd66][ci8] bf16 (d-halo baked in) ----
__global__ __launch_bounds__(256) void pack_x_kernel(
    const float* __restrict__ X, ushort* __restrict__ Xpk)
{
    int idx = blockIdx.x * 256 + threadIdx.x;   // 2,162,688 exact (8448 blocks)
    int dd  = idx % 66;
    int t   = idx / 66;
    int w   = t & 63; t >>= 6;
    int h   = t & 31; t >>= 5;
    int b   = t & 3;
    int cic = (t >> 2) & 3;
    int dp  = dd - 1;
    bool ok = (unsigned)dp < (unsigned)S_D;
    int dc  = ok ? dp : 0;                      // safe addr for pad sites
    const float* xp = X + (((long)(b * C_IN + cic * 8) * S_H + h) * S_W + w) * S_D + dc;
    u32x4 pk;
    #pragma unroll
    for (int j = 0; j < 4; ++j) {
        float lo = ok ? xp[(long)(2 * j)     * HWD] : 0.f;
        float hi = ok ? xp[(long)(2 * j + 1) * HWD] : 0.f;
        pk[j] = cvt_pk(lo, hi);
    }
    *((u32x4*)Xpk + idx) = pk;
}

// ---- main: BARRIER-FREE flat conv (AITER-flatmm style) --------------------
// R8 ablation: removing ds_read saved 40% (V2: 112.6us @REP2 vs ~186 full;
// bank-conflict 0 only there) and every phase-removal saved >35% -- the
// 2-barrier/cic structure serializes phases. Fix: since [ci8] is contiguous
// in Xpk/Wpk, MFMA fragments ARE contiguous 16B global loads. Read A and B
// fragments DIRECTLY global->VGPR (L1/L2/L3-resident: Wpk 57KB, Xpk 34.6MB).
// No LDS, no barriers, no staging: waves free-run, compiler's counted vmcnt
// pipelines loads under MFMAs, 8 waves/CU overlap the rest.
// Per tg: A ptr (linear +4096B/tg across all 28 taps*cic), B ptr from
// precomputed per-lane table (OOB h/w -> Wpk tap27 zero row, cic-advance 0);
// 8x global_load_dwordx4 with imm offsets (mi*256 / dt*256) feed 16 MFMAs.
__global__ __launch_bounds__(256, 2) void conv3d_flat_kernel(
    const ushort* __restrict__ Xpk, const ushort* __restrict__ Wpk,
    const float* __restrict__ bias, float* __restrict__ out)
{
    const int tid  = threadIdx.x;
    const int lane = tid & 63;
    const int wave = tid >> 6;
    const int nl   = lane & 15;
    const int quad = lane >> 4;

    const int blk = blockIdx.x;       // 2048 blocks = (b4, h32, wt16)
    const int wt  = blk & 15;
    const int h   = (blk >> 4) & 31;
    const int b   = blk >> 9;
    const int w0  = wt * 4;

    // ---- per-lane B pointers per tg (7), cic advances -----------------------
    const char* pb[7];
    int         advb[7];
    #pragma unroll
    for (int tg = 0; tg < 7; ++tg) {
        int tap = tg * 4 + quad;
        int tb  = tap < 27 ? tap : 0;      // pad tap: A row is zero anyway
        int kh = tb / 9, r9 = tb - kh * 9;
        int kw = r9 / 3, kd = r9 - kw * 3;
        int hp = h - 1 + kh;
        int wp = w0 + wave - 1 + kw;
        bool ok = (unsigned)hp < S_H && (unsigned)wp < S_W;
        if (ok) {
            pb[tg] = (const char*)Xpk +
                     ((((long)b * S_H + hp) * S_W + wp) * 66 + nl + kd) * 16;
            advb[tg] = XPK_CIC_STR;
        } else {
            pb[tg] = (const char*)Wpk + WZERO_OFF + nl * 16;  // zeros; +768 max stays in row
            advb[tg] = 0;
        }
    }
    // A pointer: (cic*28 + tg*4 + quad)*1024 + nl*16 is linear: +4096 per tg
    const char* pa = (const char*)Wpk + quad * 1024 + nl * 16;

    float bs[16];
    #pragma unroll
    for (int mi = 0; mi < 4; ++mi)
        #pragma unroll
        for (int r = 0; r < 4; ++r)
            bs[mi * 4 + r] = bias[mi * 16 + quad * 4 + r];

    f32x4 acc[16];
    #pragma unroll
    for (int i = 0; i < 16; ++i) acc[i] = (f32x4){0.f, 0.f, 0.f, 0.f};

    #pragma unroll 1
    for (int cic = 0; cic < 4; ++cic) {
        #pragma unroll
        for (int tg = 0; tg < 7; ++tg) {
            bf16x8 af[4], bf[4];
            #pragma unroll
            for (int mi = 0; mi < 4; ++mi)
                af[mi] = *(const bf16x8*)(pa + mi * 256);       // +16 co
            #pragma unroll
            for (int dt = 0; dt < 4; ++dt)
                bf[dt] = *(const bf16x8*)(pb[tg] + dt * 256);   // +16 d
            #pragma unroll
            for (int mi = 0; mi < 4; ++mi)
                #pragma unroll
                for (int dt = 0; dt < 4; ++dt)
                    acc[mi * 4 + dt] = __builtin_amdgcn_mfma_f32_16x16x32_bf16(
                        af[mi], bf[dt], acc[mi * 4 + dt], 0, 0, 0);
            pa += 4096;
        }
        #pragma unroll
        for (int tg = 0; tg < 7; ++tg) pb[tg] += advb[tg];
    }

    // ---- epilogue: co = mi*16 + quad*4 + r, n = (w0+wave, dt*16+nl) -------
    const int w = w0 + wave;
    #pragma unroll
    for (int mi = 0; mi < 4; ++mi) {
        #pragma unroll
        for (int dt = 0; dt < 4; ++dt) {
            f32x4 a = acc[mi * 4 + dt];
            int d0 = dt * 16 + nl;
            #pragma unroll
            for (int r = 0; r < 4; ++r) {
                int co = mi * 16 + quad * 4 + r;
                out[(((long)(b * C_OUT + co) * S_H + h) * S_W + w) * S_D + d0]
                    = a[r] + bs[mi * 4 + r];
            }
        }
    }
}

// ---- mid-tier: R5 fused kernel (94.7us verified) --------------------------
__global__ __launch_bounds__(256, 2) void conv3d_fused_kernel(
    const float* __restrict__ X, const ushort* __restrict__ Wpk,
    const float* __restrict__ Zpf,
    const float* __restrict__ bias, float* __restrict__ out)
{
    __shared__ ushort Xs[1188 * 8];
    __shared__ ushort Ws[1792 * 8];

    const int tid  = threadIdx.x;
    const int lane = tid & 63;
    const int wave = tid >> 6;
    const int nl   = lane & 15;
    const int quad = lane >> 4;

    const int blk = blockIdx.x;
    const int wt  = blk & 15;
    const int h   = (blk >> 4) & 31;
    const int b   = blk >> 9;
    const int w0  = wt * 4;

    const float* xb[5];
    int adv[5];
    #pragma unroll
    for (int k = 0; k < 5; ++k) {
        int s = tid + k * 256;
        xb[k] = Zpf; adv[k] = 0;
        if (s < 1188) {
            int hh   = s / 396;
            int r0   = s - hh * 396;
            int ww   = r0 / 66;
            int dpos = r0 - ww * 66;
            int hp  = h - 1 + hh;
            int wp2 = w0 - 1 + ww;
            int dp  = dpos - 1;
            bool ok = (unsigned)hp < S_H && (unsigned)wp2 < S_W && (unsigned)dp < S_D;
            if (ok) {
                xb[k]  = X + ((((long)b * C_IN) * S_H + hp) * S_W + wp2) * S_D + dp;
                adv[k] = HWD;
            }
        }
    }

    int a_off[7], b_off[7];
    #pragma unroll
    for (int tg = 0; tg < 7; ++tg) {
        int tap = tg * 4 + quad;
        int tb  = tap < 27 ? tap : 0;
        int kh = tb / 9;
        int r9 = tb - kh * 9;
        int kw = r9 / 3;
        int kd = r9 - kw * 3;
        a_off[tg] = (tap * 64 + nl) * 8;
        b_off[tg] = (((kh * 6 + kw + wave) * 66) + kd + nl) * 8;
    }

    float bs[16];
    #pragma unroll
    for (int mi = 0; mi < 4; ++mi)
        #pragma unroll
        for (int r = 0; r < 4; ++r)
            bs[mi * 4 + r] = bias[mi * 16 + quad * 4 + r];

    f32x4 acc[16];
    #pragma unroll
    for (int i = 0; i < 16; ++i) acc[i] = (f32x4){0.f, 0.f, 0.f, 0.f};

    float xv[5][8];

    #pragma unroll
    for (int k = 0; k < 5; ++k) {
        int s = tid + k * 256;
        if (s < 1188) {
            #pragma unroll
            for (int j = 0; j < 8; ++j)
                pin_load(xv[k][j], xb[k] + (long)j * adv[k]);
        }
    }
    __builtin_amdgcn_sched_barrier(0);
    #pragma unroll
    for (int k = 0; k < 7; ++k) {
        int s = tid + k * 256;
        dma16(Wpk + s * 8, &Ws[s * 8]);
    }
    __builtin_amdgcn_sched_barrier(0);
    asm volatile("s_waitcnt vmcnt(7)" ::: "memory");
    __builtin_amdgcn_sched_barrier(0);
    #pragma unroll
    for (int k = 0; k < 5; ++k) {
        int s = tid + k * 256;
        if (s < 1188) {
            u32x4 pk;
            #pragma unroll
            for (int j = 0; j < 4; ++j)
                pk[j] = cvt_pk(xv[k][2 * j], xv[k][2 * j + 1]);
            *(u32x4*)&Xs[s * 8] = pk;
        }
    }

    for (int cic = 0; cic < 4; ++cic) {
        __syncthreads();

        if (cic < 3) {
            #pragma unroll
            for (int k = 0; k < 5; ++k) {
                int s = tid + k * 256;
                if (s < 1188) {
                    #pragma unroll
                    for (int j = 0; j < 8; ++j)
                        pin_load(xv[k][j],
                                 xb[k] + (long)((cic + 1) * 8 + j) * adv[k]);
                }
            }
        }
        __builtin_amdgcn_sched_barrier(0);

        #pragma unroll
        for (int tg = 0; tg < 7; ++tg) {
            bf16x8 af[4], bf[4];
            #pragma unroll
            for (int mi = 0; mi < 4; ++mi)
                af[mi] = *(const bf16x8*)&Ws[a_off[tg] + mi * 128];
            #pragma unroll
            for (int dt = 0; dt < 4; ++dt)
                bf[dt] = *(const bf16x8*)&Xs[b_off[tg] + dt * 128];
            #pragma unroll
            for (int mi = 0; mi < 4; ++mi)
                #pragma unroll
                for (int dt = 0; dt < 4; ++dt)
                    acc[mi * 4 + dt] = __builtin_amdgcn_mfma_f32_16x16x32_bf16(
                        af[mi], bf[dt], acc[mi * 4 + dt], 0, 0, 0);
        }

        if (cic < 3) {
            __syncthreads();
            asm volatile("s_waitcnt vmcnt(0)" ::: "memory");
            __builtin_amdgcn_sched_barrier(0);
            {
                const ushort* src = Wpk + (long)(cic + 1) * 1792 * 8;
                #pragma unroll
                for (int k = 0; k < 7; ++k) {
                    int s = tid + k * 256;
                    dma16(src + s * 8, &Ws[s * 8]);
                }
            }
            #pragma unroll
            for (int k = 0; k < 5; ++k) {
                int s = tid + k * 256;
                if (s < 1188) {
                    u32x4 pk;
                    #pragma unroll
                    for (int j = 0; j < 4; ++j)
                        pk[j] = cvt_pk(xv[k][2 * j], xv[k][2 * j + 1]);
                    *(u32x4*)&Xs[s * 8] = pk;
                }
            }
        }
    }

    const int w = w0 + wave;
    #pragma unroll
    for (int mi = 0; mi < 4; ++mi) {
        #pragma unroll
        for (int dt = 0; dt < 4; ++dt) {
            f32x4 a = acc[mi * 4 + dt];
            int d0 = dt * 16 + nl;
            #pragma unroll
            for (int r = 0; r < 4; ++r) {
                int co = mi * 16 + quad * 4 + r;
                out[(((long)(b * C_OUT + co) * S_H + h) * S_W + w) * S_D + d0]
                    = a[r] + bs[mi * 4 + r];
            }
        }
    }
}

// ---- fallback (no workspace needed) ---------------------------------------
__global__ __launch_bounds__(256) void conv3d_mfma_fallback(
    const float* __restrict__ X, const float* __restrict__ Wt,
    const float* __restrict__ bias, float* __restrict__ out)
{
    __shared__ ushort Xs[3 * 6 * 66 * 8];
    __shared__ ushort Ws[28 * 64 * 8];

    const int tid  = threadIdx.x;
    const int lane = tid & 63;
    const int wave = tid >> 6;
    const int nl   = lane & 15;
    const int quad = lane >> 4;
    const int co_base = wave * 16;

    const int blk = blockIdx.x;
    const int wt  = blk & 15;
    const int h   = (blk >> 4) & 31;
    const int b   = blk >> 9;
    const int w0  = wt * 4;

    float bs[4];
    #pragma unroll
    for (int r = 0; r < 4; ++r) bs[r] = bias[co_base + quad * 4 + r];

    f32x4 acc[16];
    #pragma unroll
    for (int i = 0; i < 16; ++i) acc[i] = (f32x4){0.f, 0.f, 0.f, 0.f};

    for (int cic = 0; cic < 4; ++cic) {
        __syncthreads();
        for (int s = tid; s < 64 * 27; s += 256) {
            int co = s / 27;
            int t  = s - co * 27;
            const float* wp = Wt + ((long)co * C_IN + cic * 8) * 27 + t;
            bf16x8 pk;
            #pragma unroll
            for (int j = 0; j < 8; ++j) pk[j] = (short)f2bf(wp[j * 27]);
            *(bf16x8*)&Ws[(t * 64 + co) * 8] = pk;
        }
        for (int s = tid; s < 64; s += 256) {
            bf16x8 z;
            #pragma unroll
            for (int j = 0; j < 8; ++j) z[j] = 0;
            *(bf16x8*)&Ws[(27 * 64 + s) * 8] = z;
        }
        for (int s = tid; s < 1188; s += 256) {
            int hh   = s / 396;
            int r0   = s - hh * 396;
            int ww   = r0 / 66;
            int dpos = r0 - ww * 66;
            int hp = h - 1 + hh;
            int wp2 = w0 - 1 + ww;
            int dp = dpos - 1;
            bool ok = (unsigned)hp < S_H && (unsigned)wp2 < S_W && (unsigned)dp < S_D;
            int hc = min(max(hp, 0), S_H - 1);
            int wc = min(max(wp2, 0), S_W - 1);
            int dc = min(max(dp, 0), S_D - 1);
            const float* xp = X + (((long)(b * C_IN + cic * 8) * S_H + hc) * S_W + wc) * S_D + dc;
            bf16x8 pk;
            #pragma unroll
            for (int j = 0; j < 8; ++j) {
                float v = xp[(long)j * HWD];
                pk[j] = ok ? (short)f2bf(v) : (short)0;
            }
            *(bf16x8*)&Xs[s * 8] = pk;
        }
        __syncthreads();

        #pragma unroll
        for (int tg = 0; tg < 7; ++tg) {
            int tap = tg * 4 + quad;
            bf16x8 afrag = *(const bf16x8*)&Ws[(tap * 64 + co_base + nl) * 8];
            int tb = tap < 27 ? tap : 0;
            int kh = tb / 9;
            int r9 = tb - kh * 9;
            int kw = r9 / 3;
            int kd = r9 - kw * 3;
            int bbase = ((kh * 6 + kw) * 66 + kd + nl) * 8;
            #pragma unroll
            for (int wi = 0; wi < 4; ++wi) {
                #pragma unroll
                for (int dt = 0; dt < 4; ++dt) {
                    bf16x8 bfrag = *(const bf16x8*)&Xs[bbase + wi * (66 * 8) + dt * (16 * 8)];
                    acc[wi * 4 + dt] = __builtin_amdgcn_mfma_f32_16x16x32_bf16(
                        afrag, bfrag, acc[wi * 4 + dt], 0, 0, 0);
                }
            }
        }
    }

    #pragma unroll
    for (int wi = 0; wi < 4; ++wi) {
        int w = w0 + wi;
        #pragma unroll
        for (int dt = 0; dt < 4; ++dt) {
            int d0 = dt * 16 + nl;
            f32x4 a = acc[wi * 4 + dt];
            #pragma unroll
            for (int r = 0; r < 4; ++r) {
                int co = co_base + quad * 4 + r;
                out[(((long)(b * C_OUT + co) * S_H + h) * S_W + w) * S_D + d0] = a[r] + bs[r];
            }
        }
    }
}

extern "C" void kernel_launch(void* const* d_in, const int* in_sizes, int n_in,
                              void* d_out, int out_size, void* d_ws, size_t ws_size,
                              hipStream_t stream) {
    const float* X    = (const float*)d_in[0];
    const float* Wt   = (const float*)d_in[1];
    const float* bias = (const float*)d_in[2];
    float* out = (float*)d_out;

    if (ws_size >= WS_FLAT) {
        ushort* Wpk = (ushort*)d_ws;
        float*  Zpf = (float*)((char*)d_ws + ZPF_OFF);
        ushort* Xpk = (ushort*)((char*)d_ws + XPK_OFF);
        pack_w_kernel<<<dim3(28),   dim3(256), 0, stream>>>(Wt, Wpk, Zpf);
        pack_x_kernel<<<dim3(8448), dim3(256), 0, stream>>>(X, Xpk);
        conv3d_flat_kernel<<<dim3(2048), dim3(256), 0, stream>>>(Xpk, Wpk, bias, out);
    } else if (ws_size >= WS_FUSED) {
        ushort* Wpk = (ushort*)d_ws;
        float*  Zpf = (float*)((char*)d_ws + ZPF_OFF);
        pack_w_kernel<<<dim3(28), dim3(256), 0, stream>>>(Wt, Wpk, Zpf);
        conv3d_fused_kernel<<<dim3(2048), dim3(256), 0, stream>>>(X, Wpk, Zpf, bias, out);
    } else {
        conv3d_mfma_fallback<<<dim3(2048), dim3(256), 0, stream>>>(X, Wt, bias, out);
    }
}

// Round 10
// 245.878 us; speedup vs baseline: 2.3473x; 1.1095x over previous
//
#include <hip/hip_runtime.h>
#include <hip/hip_bf16.h>

typedef __attribute__((ext_vector_type(8))) short bf16x8;
typedef __attribute__((ext_vector_type(4))) float f32x4;
typedef __attribute__((ext_vector_type(4))) unsigned int u32x4;

#define C_IN  32
#define C_OUT 64
#define S_H   32
#define S_W   64
#define S_D   64
#define HWD   (S_H * S_W * S_D)   /* 131072 */

// ws layout: [Wpk 114688 B][Zpf 64 B][Xpk 34.6 MB]
// Wpk: [cic4][tap28][co64][ci8] bf16 (tap27 row = zeros, doubles as OOB target)
// Xpk: [cic4][b4][h32][w64][dd66][ci8] bf16, dd = d+1 (d-halo baked in)
#define WPK_BYTES   (4 * 28 * 64 * 8 * 2)        /* 114688 */
#define ZPF_OFF     WPK_BYTES
#define XPK_OFF     (WPK_BYTES + 64)             /* 114752, 16B aligned */
#define XPK_SITES   (4 * 4 * 32 * 64 * 66)       /* 2,162,688 */
#define XPK_BYTES   ((size_t)XPK_SITES * 16)     /* 34,603,008 */
#define XPK_CIC_STR (4 * 32 * 64 * 66 * 16)      /* 8,650,752 B */
#define WS_FLAT     ((size_t)XPK_OFF + XPK_BYTES)
#define WS_FUSED    ((size_t)WPK_BYTES + 64)
#define WZERO_OFF   (27 * 1024)                  /* cic0 tap27 zero row (1 KB) */

__device__ __forceinline__ ushort f2bf(float f) {
    unsigned u = __builtin_bit_cast(unsigned, f);
    unsigned r = (u + 0x7FFFu + ((u >> 16) & 1u)) >> 16;  // RNE
    return (ushort)r;
}

// packed f32x2 -> bf16x2 (RNE), single VALU op
__device__ __forceinline__ unsigned cvt_pk(float lo, float hi) {
    unsigned r;
    asm("v_cvt_pk_bf16_f32 %0, %1, %2" : "=v"(r) : "v"(lo), "v"(hi));
    return r;
}

typedef const __attribute__((address_space(1))) unsigned int* dma_gptr;
typedef __attribute__((address_space(3))) unsigned int* dma_lptr;

__device__ __forceinline__ void dma16(const void* g, void* l) {
    __builtin_amdgcn_global_load_lds((dma_gptr)g, (dma_lptr)l, 16, 0, 0);
}

__device__ __forceinline__ void pin_load(float& dst, const float* p) {
    asm volatile("global_load_dword %0, %1, off" : "=v"(dst) : "v"(p));
}

// ---- prep: pack weights [cic][tap28][co64][ci8] bf16; zero-page ----------
__global__ __launch_bounds__(256) void pack_w_kernel(
    const float* __restrict__ Wt, ushort* __restrict__ Wpk, float* __restrict__ Zpf)
{
    int idx = blockIdx.x * 256 + threadIdx.x;       // 4*28*64 = 7168
    int cic = idx / 1792;
    int r   = idx - cic * 1792;
    int tap = r >> 6;
    int co  = r & 63;
    bf16x8 pk;
    #pragma unroll
    for (int j = 0; j < 8; ++j)
        pk[j] = (tap < 27) ? (short)f2bf(Wt[((long)co * C_IN + cic * 8 + j) * 27 + tap])
                           : (short)0;
    *((bf16x8*)Wpk + idx) = pk;
    if (blockIdx.x == 0 && threadIdx.x < 16) Zpf[threadIdx.x] = 0.f;
}

// ---- prep: pack X -> [cic][b][h][w][dd66][ci8] bf16 (d-halo baked in) ----
__global__ __launch_bounds__(256) void pack_x_kernel(
    const float* __restrict__ X, ushort* __restrict__ Xpk)
{
    int idx = blockIdx.x * 256 + threadIdx.x;   // 2,162,688 exact (8448 blocks)
    int dd  = idx % 66;
    int t   = idx / 66;
    int w   = t & 63; t >>= 6;
    int h   = t & 31; t >>= 5;
    int b   = t & 3;
    int cic = (t >> 2) & 3;
    int dp  = dd - 1;
    bool ok = (unsigned)dp < (unsigned)S_D;
    int dc  = ok ? dp : 0;                      // safe addr for pad sites
    const float* xp = X + (((long)(b * C_IN + cic * 8) * S_H + h) * S_W + w) * S_D + dc;
    u32x4 pk;
    #pragma unroll
    for (int j = 0; j < 4; ++j) {
        float lo = ok ? xp[(long)(2 * j)     * HWD] : 0.f;
        float hi = ok ? xp[(long)(2 * j + 1) * HWD] : 0.f;
        pk[j] = cvt_pk(lo, hi);
    }
    *((u32x4*)Xpk + idx) = pk;
}

// ---- main: HYBRID conv -- A from LDS, B direct global->VGPR ---------------
// R8 ablation: fused kernel's cost center = 224 ds_read_b128/wave (~57us,
// removing them saved 40%). R9 flat: all operands via L1 -> 94KB working set
// thrashes 32KB L1 -> latency-bound at 103us (MfmaUtil 23, VALU 12).
// Hybrid splits the operand streams across the two independent pipes:
//  - A (Wpk, 28KB/cic, L2-hot): global_load_lds -> LDS, DOUBLE-BUFFERED so
//    only ONE barrier per cic (dma writes buf^1 while reads hit buf; the
//    next top barrier both drains the dma and closes the WAR window).
//    LDS reads drop to 112 b128/wave (~28us aggregate, half of fused).
//  - B (Xpk): direct 16B global loads. Per-block per-cic X footprint is
//    19KB (x2 blocks = 38KB ~ L1) with 23x in-block reuse -> L1-resident.
//    Tracked loads, tiny reg pressure -> compiler pipelines them freely.
// No X staging, no staging VALU, no pinned asm. 4 barriers total per block.
// Bound = max(MFMA 29us, LDS-A 28us, L1-B ~12us), overlapped.
__global__ __launch_bounds__(256, 2) void conv3d_hyb_kernel(
    const ushort* __restrict__ Xpk, const ushort* __restrict__ Wpk,
    const float* __restrict__ bias, float* __restrict__ out)
{
    __shared__ ushort Ws[2][1792 * 8];   // [buf][tap28][co64][ci8]  2x28672 B

    const int tid  = threadIdx.x;
    const int lane = tid & 63;
    const int wave = tid >> 6;
    const int nl   = lane & 15;
    const int quad = lane >> 4;

    const int blk = blockIdx.x;       // 2048 blocks = (b4, h32, wt16)
    const int wt  = blk & 15;
    const int h   = (blk >> 4) & 31;
    const int b   = blk >> 9;
    const int w0  = wt * 4;

    // ---- per-lane B pointers per tg (7), cic advances ---------------------
    const char* pb[7];
    int         advb[7];
    #pragma unroll
    for (int tg = 0; tg < 7; ++tg) {
        int tap = tg * 4 + quad;
        int tb  = tap < 27 ? tap : 0;      // pad tap: A row is zero anyway
        int kh = tb / 9, r9 = tb - kh * 9;
        int kw = r9 / 3, kd = r9 - kw * 3;
        int hp = h - 1 + kh;
        int wp = w0 + wave - 1 + kw;
        bool ok = (unsigned)hp < S_H && (unsigned)wp < S_W;
        if (ok) {
            pb[tg] = (const char*)Xpk +
                     ((((long)b * S_H + hp) * S_W + wp) * 66 + nl + kd) * 16;
            advb[tg] = XPK_CIC_STR;
        } else {
            pb[tg] = (const char*)Wpk + WZERO_OFF + nl * 16;  // zeros; +768 max in row
            advb[tg] = 0;
        }
    }

    // ---- per-tg A LDS byte offsets (within one W buffer) ------------------
    int a_off[7];
    #pragma unroll
    for (int tg = 0; tg < 7; ++tg)
        a_off[tg] = ((tg * 4 + quad) * 64 + nl) * 16;

    float bs[16];
    #pragma unroll
    for (int mi = 0; mi < 4; ++mi)
        #pragma unroll
        for (int r = 0; r < 4; ++r)
            bs[mi * 4 + r] = bias[mi * 16 + quad * 4 + r];

    f32x4 acc[16];
    #pragma unroll
    for (int i = 0; i < 16; ++i) acc[i] = (f32x4){0.f, 0.f, 0.f, 0.f};

    // ---- prologue: W chunk 0 DMA into buf 0 -------------------------------
    #pragma unroll
    for (int k = 0; k < 7; ++k) {
        int s = tid + k * 256;
        dma16(Wpk + s * 8, &Ws[0][s * 8]);
    }

    #pragma unroll 1
    for (int cic = 0; cic < 4; ++cic) {
        __syncthreads();                 // drains W[cic] DMA; closes WAR on buf

        // stage W[cic+1] into the other buffer (no barrier until next top)
        if (cic < 3) {
            const ushort* src = Wpk + (long)(cic + 1) * 1792 * 8;
            #pragma unroll
            for (int k = 0; k < 7; ++k) {
                int s = tid + k * 256;
                dma16(src + s * 8, &Ws[(cic + 1) & 1][s * 8]);
            }
        }

        const ushort* wb = Ws[cic & 1];
        #pragma unroll
        for (int tg = 0; tg < 7; ++tg) {
            bf16x8 af[4], bf[4];
            #pragma unroll
            for (int mi = 0; mi < 4; ++mi)
                af[mi] = *(const bf16x8*)((const char*)wb + a_off[tg] + mi * 256);
            #pragma unroll
            for (int dt = 0; dt < 4; ++dt)
                bf[dt] = *(const bf16x8*)(pb[tg] + dt * 256);   // +16 d
            #pragma unroll
            for (int mi = 0; mi < 4; ++mi)
                #pragma unroll
                for (int dt = 0; dt < 4; ++dt)
                    acc[mi * 4 + dt] = __builtin_amdgcn_mfma_f32_16x16x32_bf16(
                        af[mi], bf[dt], acc[mi * 4 + dt], 0, 0, 0);
        }
        #pragma unroll
        for (int tg = 0; tg < 7; ++tg) pb[tg] += advb[tg];
    }

    // ---- epilogue: co = mi*16 + quad*4 + r, n = (w0+wave, dt*16+nl) -------
    const int w = w0 + wave;
    #pragma unroll
    for (int mi = 0; mi < 4; ++mi) {
        #pragma unroll
        for (int dt = 0; dt < 4; ++dt) {
            f32x4 a = acc[mi * 4 + dt];
            int d0 = dt * 16 + nl;
            #pragma unroll
            for (int r = 0; r < 4; ++r) {
                int co = mi * 16 + quad * 4 + r;
                out[(((long)(b * C_OUT + co) * S_H + h) * S_W + w) * S_D + d0]
                    = a[r] + bs[mi * 4 + r];
            }
        }
    }
}

// ---- mid-tier: R5 fused kernel (94.7us verified) --------------------------
__global__ __launch_bounds__(256, 2) void conv3d_fused_kernel(
    const float* __restrict__ X, const ushort* __restrict__ Wpk,
    const float* __restrict__ Zpf,
    const float* __restrict__ bias, float* __restrict__ out)
{
    __shared__ ushort Xs[1188 * 8];
    __shared__ ushort Ws[1792 * 8];

    const int tid  = threadIdx.x;
    const int lane = tid & 63;
    const int wave = tid >> 6;
    const int nl   = lane & 15;
    const int quad = lane >> 4;

    const int blk = blockIdx.x;
    const int wt  = blk & 15;
    const int h   = (blk >> 4) & 31;
    const int b   = blk >> 9;
    const int w0  = wt * 4;

    const float* xb[5];
    int adv[5];
    #pragma unroll
    for (int k = 0; k < 5; ++k) {
        int s = tid + k * 256;
        xb[k] = Zpf; adv[k] = 0;
        if (s < 1188) {
            int hh   = s / 396;
            int r0   = s - hh * 396;
            int ww   = r0 / 66;
            int dpos = r0 - ww * 66;
            int hp  = h - 1 + hh;
            int wp2 = w0 - 1 + ww;
            int dp  = dpos - 1;
            bool ok = (unsigned)hp < S_H && (unsigned)wp2 < S_W && (unsigned)dp < S_D;
            if (ok) {
                xb[k]  = X + ((((long)b * C_IN) * S_H + hp) * S_W + wp2) * S_D + dp;
                adv[k] = HWD;
            }
        }
    }

    int a_off[7], b_off[7];
    #pragma unroll
    for (int tg = 0; tg < 7; ++tg) {
        int tap = tg * 4 + quad;
        int tb  = tap < 27 ? tap : 0;
        int kh = tb / 9;
        int r9 = tb - kh * 9;
        int kw = r9 / 3;
        int kd = r9 - kw * 3;
        a_off[tg] = (tap * 64 + nl) * 8;
        b_off[tg] = (((kh * 6 + kw + wave) * 66) + kd + nl) * 8;
    }

    float bs[16];
    #pragma unroll
    for (int mi = 0; mi < 4; ++mi)
        #pragma unroll
        for (int r = 0; r < 4; ++r)
            bs[mi * 4 + r] = bias[mi * 16 + quad * 4 + r];

    f32x4 acc[16];
    #pragma unroll
    for (int i = 0; i < 16; ++i) acc[i] = (f32x4){0.f, 0.f, 0.f, 0.f};

    float xv[5][8];

    #pragma unroll
    for (int k = 0; k < 5; ++k) {
        int s = tid + k * 256;
        if (s < 1188) {
            #pragma unroll
            for (int j = 0; j < 8; ++j)
                pin_load(xv[k][j], xb[k] + (long)j * adv[k]);
        }
    }
    __builtin_amdgcn_sched_barrier(0);
    #pragma unroll
    for (int k = 0; k < 7; ++k) {
        int s = tid + k * 256;
        dma16(Wpk + s * 8, &Ws[s * 8]);
    }
    __builtin_amdgcn_sched_barrier(0);
    asm volatile("s_waitcnt vmcnt(7)" ::: "memory");
    __builtin_amdgcn_sched_barrier(0);
    #pragma unroll
    for (int k = 0; k < 5; ++k) {
        int s = tid + k * 256;
        if (s < 1188) {
            u32x4 pk;
            #pragma unroll
            for (int j = 0; j < 4; ++j)
                pk[j] = cvt_pk(xv[k][2 * j], xv[k][2 * j + 1]);
            *(u32x4*)&Xs[s * 8] = pk;
        }
    }

    for (int cic = 0; cic < 4; ++cic) {
        __syncthreads();

        if (cic < 3) {
            #pragma unroll
            for (int k = 0; k < 5; ++k) {
                int s = tid + k * 256;
                if (s < 1188) {
                    #pragma unroll
                    for (int j = 0; j < 8; ++j)
                        pin_load(xv[k][j],
                                 xb[k] + (long)((cic + 1) * 8 + j) * adv[k]);
                }
            }
        }
        __builtin_amdgcn_sched_barrier(0);

        #pragma unroll
        for (int tg = 0; tg < 7; ++tg) {
            bf16x8 af[4], bf[4];
            #pragma unroll
            for (int mi = 0; mi < 4; ++mi)
                af[mi] = *(const bf16x8*)&Ws[a_off[tg] + mi * 128];
            #pragma unroll
            for (int dt = 0; dt < 4; ++dt)
                bf[dt] = *(const bf16x8*)&Xs[b_off[tg] + dt * 128];
            #pragma unroll
            for (int mi = 0; mi < 4; ++mi)
                #pragma unroll
                for (int dt = 0; dt < 4; ++dt)
                    acc[mi * 4 + dt] = __builtin_amdgcn_mfma_f32_16x16x32_bf16(
                        af[mi], bf[dt], acc[mi * 4 + dt], 0, 0, 0);
        }

        if (cic < 3) {
            __syncthreads();
            asm volatile("s_waitcnt vmcnt(0)" ::: "memory");
            __builtin_amdgcn_sched_barrier(0);
            {
                const ushort* src = Wpk + (long)(cic + 1) * 1792 * 8;
                #pragma unroll
                for (int k = 0; k < 7; ++k) {
                    int s = tid + k * 256;
                    dma16(src + s * 8, &Ws[s * 8]);
                }
            }
            #pragma unroll
            for (int k = 0; k < 5; ++k) {
                int s = tid + k * 256;
                if (s < 1188) {
                    u32x4 pk;
                    #pragma unroll
                    for (int j = 0; j < 4; ++j)
                        pk[j] = cvt_pk(xv[k][2 * j], xv[k][2 * j + 1]);
                    *(u32x4*)&Xs[s * 8] = pk;
                }
            }
        }
    }

    const int w = w0 + wave;
    #pragma unroll
    for (int mi = 0; mi < 4; ++mi) {
        #pragma unroll
        for (int dt = 0; dt < 4; ++dt) {
            f32x4 a = acc[mi * 4 + dt];
            int d0 = dt * 16 + nl;
            #pragma unroll
            for (int r = 0; r < 4; ++r) {
                int co = mi * 16 + quad * 4 + r;
                out[(((long)(b * C_OUT + co) * S_H + h) * S_W + w) * S_D + d0]
                    = a[r] + bs[mi * 4 + r];
            }
        }
    }
}

// ---- fallback (no workspace needed) ---------------------------------------
__global__ __launch_bounds__(256) void conv3d_mfma_fallback(
    const float* __restrict__ X, const float* __restrict__ Wt,
    const float* __restrict__ bias, float* __restrict__ out)
{
    __shared__ ushort Xs[3 * 6 * 66 * 8];
    __shared__ ushort Ws[28 * 64 * 8];

    const int tid  = threadIdx.x;
    const int lane = tid & 63;
    const int wave = tid >> 6;
    const int nl   = lane & 15;
    const int quad = lane >> 4;
    const int co_base = wave * 16;

    const int blk = blockIdx.x;
    const int wt  = blk & 15;
    const int h   = (blk >> 4) & 31;
    const int b   = blk >> 9;
    const int w0  = wt * 4;

    float bs[4];
    #pragma unroll
    for (int r = 0; r < 4; ++r) bs[r] = bias[co_base + quad * 4 + r];

    f32x4 acc[16];
    #pragma unroll
    for (int i = 0; i < 16; ++i) acc[i] = (f32x4){0.f, 0.f, 0.f, 0.f};

    for (int cic = 0; cic < 4; ++cic) {
        __syncthreads();
        for (int s = tid; s < 64 * 27; s += 256) {
            int co = s / 27;
            int t  = s - co * 27;
            const float* wp = Wt + ((long)co * C_IN + cic * 8) * 27 + t;
            bf16x8 pk;
            #pragma unroll
            for (int j = 0; j < 8; ++j) pk[j] = (short)f2bf(wp[j * 27]);
            *(bf16x8*)&Ws[(t * 64 + co) * 8] = pk;
        }
        for (int s = tid; s < 64; s += 256) {
            bf16x8 z;
            #pragma unroll
            for (int j = 0; j < 8; ++j) z[j] = 0;
            *(bf16x8*)&Ws[(27 * 64 + s) * 8] = z;
        }
        for (int s = tid; s < 1188; s += 256) {
            int hh   = s / 396;
            int r0   = s - hh * 396;
            int ww   = r0 / 66;
            int dpos = r0 - ww * 66;
            int hp = h - 1 + hh;
            int wp2 = w0 - 1 + ww;
            int dp = dpos - 1;
            bool ok = (unsigned)hp < S_H && (unsigned)wp2 < S_W && (unsigned)dp < S_D;
            int hc = min(max(hp, 0), S_H - 1);
            int wc = min(max(wp2, 0), S_W - 1);
            int dc = min(max(dp, 0), S_D - 1);
            const float* xp = X + (((long)(b * C_IN + cic * 8) * S_H + hc) * S_W + wc) * S_D + dc;
            bf16x8 pk;
            #pragma unroll
            for (int j = 0; j < 8; ++j) {
                float v = xp[(long)j * HWD];
                pk[j] = ok ? (short)f2bf(v) : (short)0;
            }
            *(bf16x8*)&Xs[s * 8] = pk;
        }
        __syncthreads();

        #pragma unroll
        for (int tg = 0; tg < 7; ++tg) {
            int tap = tg * 4 + quad;
            bf16x8 afrag = *(const bf16x8*)&Ws[(tap * 64 + co_base + nl) * 8];
            int tb = tap < 27 ? tap : 0;
            int kh = tb / 9;
            int r9 = tb - kh * 9;
            int kw = r9 / 3;
            int kd = r9 - kw * 3;
            int bbase = ((kh * 6 + kw) * 66 + kd + nl) * 8;
            #pragma unroll
            for (int wi = 0; wi < 4; ++wi) {
                #pragma unroll
                for (int dt = 0; dt < 4; ++dt) {
                    bf16x8 bfrag = *(const bf16x8*)&Xs[bbase + wi * (66 * 8) + dt * (16 * 8)];
                    acc[wi * 4 + dt] = __builtin_amdgcn_mfma_f32_16x16x32_bf16(
                        afrag, bfrag, acc[wi * 4 + dt], 0, 0, 0);
                }
            }
        }
    }

    #pragma unroll
    for (int wi = 0; wi < 4; ++wi) {
        int w = w0 + wi;
        #pragma unroll
        for (int dt = 0; dt < 4; ++dt) {
            int d0 = dt * 16 + nl;
            f32x4 a = acc[wi * 4 + dt];
            #pragma unroll
            for (int r = 0; r < 4; ++r) {
                int co = co_base + quad * 4 + r;
                out[(((long)(b * C_OUT + co) * S_H + h) * S_W + w) * S_D + d0] = a[r] + bs[r];
            }
        }
    }
}

extern "C" void kernel_launch(void* const* d_in, const int* in_sizes, int n_in,
                              void* d_out, int out_size, void* d_ws, size_t ws_size,
                              hipStream_t stream) {
    const float* X    = (const float*)d_in[0];
    const float* Wt   = (const float*)d_in[1];
    const float* bias = (const float*)d_in[2];
    float* out = (float*)d_out;

    if (ws_size >= WS_FLAT) {
        ushort* Wpk = (ushort*)d_ws;
        float*  Zpf = (float*)((char*)d_ws + ZPF_OFF);
        ushort* Xpk = (ushort*)((char*)d_ws + XPK_OFF);
        pack_w_kernel<<<dim3(28),   dim3(256), 0, stream>>>(Wt, Wpk, Zpf);
        pack_x_kernel<<<dim3(8448), dim3(256), 0, stream>>>(X, Xpk);
        conv3d_hyb_kernel<<<dim3(2048), dim3(256), 0, stream>>>(Xpk, Wpk, bias, out);
    } else if (ws_size >= WS_FUSED) {
        ushort* Wpk = (ushort*)d_ws;
        float*  Zpf = (float*)((char*)d_ws + ZPF_OFF);
        pack_w_kernel<<<dim3(28), dim3(256), 0, stream>>>(Wt, Wpk, Zpf);
        conv3d_fused_kernel<<<dim3(2048), dim3(256), 0, stream>>>(X, Wpk, Zpf, bias, out);
    } else {
        conv3d_mfma_fallback<<<dim3(2048), dim3(256), 0, stream>>>(X, Wt, bias, out);
    }
}